// Round 1
// baseline (356.477 us; speedup 1.0000x reference)
//
#include <hip/hip_runtime.h>

#define NUM_USERS 200000
#define NUM_ITEMS 100000
#define NUM_NODES 300000
#define NUM_EDGES 600000
#define DIM      128
#define BATCH    16384
#define NSLOTS   (2 * BATCH)   // 32768 candidate slots (user + item per batch element)

// ---- K1: node -> slot map via CAS dedup. map pre-set to -1 by memset(0xFF). ----
__global__ void build_map(const int* __restrict__ uidx, const int* __restrict__ iidx,
                          int* __restrict__ map) {
    int t = blockIdx.x * 256 + threadIdx.x;
    if (t >= NSLOTS) return;
    int node = (t < BATCH) ? uidx[t] : (NUM_USERS + iidx[t - BATCH]);
    atomicCAS(&map[node], -1, t);   // winner's batch-position becomes the node's slot
}

// ---- K2: sparse edge scatter. Only edges whose dst is a needed node contribute. ----
// 32 threads per edge, each thread handles 4 floats (float4 gather + 4 atomicAdd).
__global__ void edge_scatter(const int* __restrict__ edges, const int* __restrict__ map,
                             const float* __restrict__ uemb, const float* __restrict__ iemb,
                             float* __restrict__ agg) {
    int e = blockIdx.x * 8 + (threadIdx.x >> 5);
    if (e >= NUM_EDGES) return;
    int lane = threadIdx.x & 31;
    int dst = edges[NUM_EDGES + e];        // edge_index[1][e]
    int s = map[dst];
    if (s < 0) return;                     // ~89% of edges exit here
    int src = edges[e];                    // edge_index[0][e]
    const float* row = (src < NUM_USERS) ? (uemb + (size_t)src * DIM)
                                         : (iemb + (size_t)(src - NUM_USERS) * DIM);
    float4 v = ((const float4*)row)[lane];
    float* d = agg + (size_t)s * DIM + lane * 4;
    atomicAdd(d + 0, v.x);
    atomicAdd(d + 1, v.y);
    atomicAdd(d + 2, v.z);
    atomicAdd(d + 3, v.w);
}

// ---- K3: prop[s][j] = b[j] + sum_k agg[s][k] * W[j][k]  (x @ W.T + b) ----
// 128 threads/block, thread j owns output column j and keeps W row j in 128 VGPRs.
// agg tile staged in LDS; inner reads are wave-wide broadcasts (conflict-free).
#define SLOTS_PER_BLOCK 32
__global__ __launch_bounds__(128) void transform(const float* __restrict__ agg,
                                                 const float* __restrict__ W,
                                                 const float* __restrict__ bias,
                                                 float* __restrict__ prop) {
    __shared__ float lds[SLOTS_PER_BLOCK * DIM];
    int j = threadIdx.x;                       // 0..127: output column
    int base = blockIdx.x * SLOTS_PER_BLOCK;

    float4 wj[DIM / 4];
    const float4* wrow = (const float4*)(W + j * DIM);
#pragma unroll
    for (int kk = 0; kk < DIM / 4; ++kk) wj[kk] = wrow[kk];
    float bj = bias[j];

    const float4* ag = (const float4*)(agg + (size_t)base * DIM);
    float4* l4 = (float4*)lds;
#pragma unroll
    for (int idx = 0; idx < SLOTS_PER_BLOCK * DIM / 4; idx += 128)
        l4[idx + j] = ag[idx + j];
    __syncthreads();

    for (int s = 0; s < SLOTS_PER_BLOCK; ++s) {
        const float4* arow = (const float4*)(lds + s * DIM);
        float acc = bj;
#pragma unroll
        for (int kk = 0; kk < DIM / 4; ++kk) {
            float4 a = arow[kk];               // broadcast LDS read (same addr all lanes)
            acc += a.x * wj[kk].x + a.y * wj[kk].y + a.z * wj[kk].z + a.w * wj[kk].w;
        }
        prop[(size_t)(base + s) * DIM + j] = acc;
    }
}

// ---- K4: out[b] = dot(prop[slot(user)], prop[slot(item)]) ; one wave per output ----
__global__ void final_dot(const int* __restrict__ uidx, const int* __restrict__ iidx,
                          const int* __restrict__ map, const float* __restrict__ prop,
                          float* __restrict__ out) {
    int o = blockIdx.x * 4 + (threadIdx.x >> 6);
    if (o >= BATCH) return;
    int lane = threadIdx.x & 63;
    int su = map[uidx[o]];
    int si = map[NUM_USERS + iidx[o]];
    float2 a = ((const float2*)(prop + (size_t)su * DIM))[lane];
    float2 c = ((const float2*)(prop + (size_t)si * DIM))[lane];
    float v = a.x * c.x + a.y * c.y;
#pragma unroll
    for (int off = 32; off > 0; off >>= 1) v += __shfl_down(v, off);
    if (lane == 0) out[o] = v;
}

extern "C" void kernel_launch(void* const* d_in, const int* in_sizes, int n_in,
                              void* d_out, int out_size, void* d_ws, size_t ws_size,
                              hipStream_t stream) {
    const int*   uidx  = (const int*)d_in[0];
    const int*   iidx  = (const int*)d_in[1];
    const float* uemb  = (const float*)d_in[2];
    const float* iemb  = (const float*)d_in[3];
    const float* W     = (const float*)d_in[4];
    const float* bias  = (const float*)d_in[5];
    const int*   edges = (const int*)d_in[6];
    float*       out   = (float*)d_out;

    char* ws = (char*)d_ws;
    int*   map  = (int*)ws;                                    // 300000 * 4 B = 1.2 MB
    float* agg  = (float*)(ws + (1 << 21));                    // 32768*128*4 = 16 MB
    float* prop = (float*)(ws + (1 << 21) + (size_t)NSLOTS * DIM * 4);

    hipMemsetAsync(map, 0xFF, NUM_NODES * sizeof(int), stream);          // map = -1
    hipMemsetAsync(agg, 0, (size_t)NSLOTS * DIM * sizeof(float), stream);

    build_map<<<(NSLOTS + 255) / 256, 256, 0, stream>>>(uidx, iidx, map);
    edge_scatter<<<(NUM_EDGES + 7) / 8, 256, 0, stream>>>(edges, map, uemb, iemb, agg);
    transform<<<NSLOTS / SLOTS_PER_BLOCK, 128, 0, stream>>>(agg, W, bias, prop);
    final_dot<<<(BATCH + 3) / 4, 256, 0, stream>>>(uidx, iidx, map, prop, out);
}

// Round 2
// 325.390 us; speedup vs baseline: 1.0955x; 1.0955x over previous
//
#include <hip/hip_runtime.h>

#define NUM_USERS 200000
#define NUM_ITEMS 100000
#define NUM_NODES 300000
#define NUM_EDGES 600000
#define DIM      128
#define BATCH    16384
#define NSLOTS   (2 * BATCH)   // 32768 candidate slots
#define CAP      32            // max in-degree captured per slot (Poisson(2) -> max ~14)

// ---- K1: node -> slot map via CAS dedup. map pre-set to -1 by memset(0xFF). ----
__global__ void build_map(const int* __restrict__ uidx, const int* __restrict__ iidx,
                          int* __restrict__ map) {
    int t = blockIdx.x * 256 + threadIdx.x;
    if (t >= NSLOTS) return;
    int node = (t < BATCH) ? uidx[t] : (NUM_USERS + iidx[t - BATCH]);
    atomicCAS(&map[node], -1, t);
}

// ---- K2: bucket contributing edges by destination slot. ----
// One int atomic per contributing edge (~62k total) on an L2-resident counter array,
// instead of 128 float atomics per edge.
__global__ void bin_edges(const int* __restrict__ edges, const int* __restrict__ map,
                          int* __restrict__ cnt, int* __restrict__ bucket) {
    int e = blockIdx.x * 256 + threadIdx.x;
    if (e >= NUM_EDGES) return;
    int dst = edges[NUM_EDGES + e];
    int s = map[dst];
    if (s < 0) return;                    // ~90% of edges exit here
    int src = edges[e];
    int p = atomicAdd(&cnt[s], 1);
    if (p < CAP) bucket[s * CAP + p] = src;
}

// ---- K3: fused gather + transform. ----
// Stage A: each wave gathers its slots' source rows (coalesced float2/lane) into
//          registers, writes the summed row to LDS.
// Stage B: thread j holds W row j in VGPRs; LDS reads are wave-wide broadcasts.
#define SPB 32   // slots per block
__global__ __launch_bounds__(256) void gather_transform(
        const int* __restrict__ cnt, const int* __restrict__ bucket,
        const float* __restrict__ uemb, const float* __restrict__ iemb,
        const float* __restrict__ W, const float* __restrict__ bias,
        float* __restrict__ prop) {
    __shared__ float lds[SPB * DIM];
    int base = blockIdx.x * SPB;
    int wave = threadIdx.x >> 6;          // 0..3
    int lane = threadIdx.x & 63;

    // Stage A: 4 waves x 8 slots each; lane covers 2 floats of the 128-wide row.
    for (int i = 0; i < SPB / 4; ++i) {
        int s = wave * (SPB / 4) + i;
        int n = cnt[base + s]; if (n > CAP) n = CAP;
        float2 acc = {0.f, 0.f};
        for (int k = 0; k < n; ++k) {
            int src = bucket[(base + s) * CAP + k];
            const float* row = (src < NUM_USERS) ? uemb + (size_t)src * DIM
                                                 : iemb + (size_t)(src - NUM_USERS) * DIM;
            float2 v = ((const float2*)row)[lane];
            acc.x += v.x; acc.y += v.y;
        }
        ((float2*)(lds + s * DIM))[lane] = acc;   // 8B stride: 2-way bank alias = free
    }
    __syncthreads();

    // Stage B: two 128-thread halves, each transforms 16 slots.
    int j = threadIdx.x & 127;            // output column
    int half = threadIdx.x >> 7;          // 0/1
    float4 wj[DIM / 4];
    const float4* wrow = (const float4*)(W + j * DIM);
#pragma unroll
    for (int kk = 0; kk < DIM / 4; ++kk) wj[kk] = wrow[kk];
    float bj = bias[j];

    for (int si = 0; si < SPB / 2; ++si) {
        int s = half * (SPB / 2) + si;
        const float4* arow = (const float4*)(lds + s * DIM);
        float acc = bj;
#pragma unroll
        for (int kk = 0; kk < DIM / 4; ++kk) {
            float4 a = arow[kk];          // broadcast LDS read (uniform addr) — conflict-free
            acc += a.x * wj[kk].x + a.y * wj[kk].y + a.z * wj[kk].z + a.w * wj[kk].w;
        }
        prop[(size_t)(base + s) * DIM + j] = acc;
    }
}

// ---- K4: out[b] = dot(prop[slot(user)], prop[slot(item)]) ; one wave per output ----
__global__ void final_dot(const int* __restrict__ uidx, const int* __restrict__ iidx,
                          const int* __restrict__ map, const float* __restrict__ prop,
                          float* __restrict__ out) {
    int o = blockIdx.x * 4 + (threadIdx.x >> 6);
    if (o >= BATCH) return;
    int lane = threadIdx.x & 63;
    int su = map[uidx[o]];
    int si = map[NUM_USERS + iidx[o]];
    float2 a = ((const float2*)(prop + (size_t)su * DIM))[lane];
    float2 c = ((const float2*)(prop + (size_t)si * DIM))[lane];
    float v = a.x * c.x + a.y * c.y;
#pragma unroll
    for (int off = 32; off > 0; off >>= 1) v += __shfl_down(v, off);
    if (lane == 0) out[o] = v;
}

extern "C" void kernel_launch(void* const* d_in, const int* in_sizes, int n_in,
                              void* d_out, int out_size, void* d_ws, size_t ws_size,
                              hipStream_t stream) {
    const int*   uidx  = (const int*)d_in[0];
    const int*   iidx  = (const int*)d_in[1];
    const float* uemb  = (const float*)d_in[2];
    const float* iemb  = (const float*)d_in[3];
    const float* W     = (const float*)d_in[4];
    const float* bias  = (const float*)d_in[5];
    const int*   edges = (const int*)d_in[6];
    float*       out   = (float*)d_out;

    char* ws = (char*)d_ws;
    int*   map    = (int*)ws;                          // 300000*4 = 1.2 MB
    int*   cnt    = (int*)(ws + (2u << 20));           // 32768*4 = 128 KB
    int*   bucket = (int*)(ws + (3u << 20));           // 32768*32*4 = 4 MB
    float* prop   = (float*)(ws + (8u << 20));         // 32768*128*4 = 16 MB

    hipMemsetAsync(map, 0xFF, NUM_NODES * sizeof(int), stream);   // map = -1
    hipMemsetAsync(cnt, 0, NSLOTS * sizeof(int), stream);

    build_map<<<(NSLOTS + 255) / 256, 256, 0, stream>>>(uidx, iidx, map);
    bin_edges<<<(NUM_EDGES + 255) / 256, 256, 0, stream>>>(edges, map, cnt, bucket);
    gather_transform<<<NSLOTS / SPB, 256, 0, stream>>>(cnt, bucket, uemb, iemb, W, bias, prop);
    final_dot<<<(BATCH + 3) / 4, 256, 0, stream>>>(uidx, iidx, map, prop, out);
}

// Round 3
// 238.156 us; speedup vs baseline: 1.4968x; 1.3663x over previous
//
#include <hip/hip_runtime.h>

#define NUM_USERS 200000
#define NUM_ITEMS 100000
#define NUM_NODES 300000
#define NUM_EDGES 600000
#define DIM      128
#define BATCH    16384
#define NSLOTS   (2 * BATCH)   // 32768 candidate slots
#define CAP      32            // max in-degree captured (Poisson(2): P(>32) ~ 1e-27)

// ---- K1: node -> slot map via CAS dedup. map pre-set to -1 by memset(0xFF). ----
__global__ void build_map(const int* __restrict__ uidx, const int* __restrict__ iidx,
                          int* __restrict__ map) {
    int t = blockIdx.x * 256 + threadIdx.x;
    if (t >= NSLOTS) return;
    int node = (t < BATCH) ? uidx[t] : (NUM_USERS + iidx[t - BATCH]);
    atomicCAS(&map[node], -1, t);
}

// ---- K2: bucket contributing edges by destination slot (one int atomic/edge). ----
__global__ void bin_edges(const int* __restrict__ edges, const int* __restrict__ map,
                          int* __restrict__ cnt, int* __restrict__ bucket) {
    int e = blockIdx.x * 256 + threadIdx.x;
    if (e >= NUM_EDGES) return;
    int dst = edges[NUM_EDGES + e];
    int s = map[dst];
    if (s < 0) return;                    // ~90% exit
    int src = edges[e];
    int p = atomicAdd(&cnt[s], 1);
    if (p < CAP) bucket[s * CAP + p] = src;
}

// ---- K3a: gather. One wave per slot; first 4 row-loads issued in parallel. ----
// bucket entries beyond cnt hold 0xAA poison (negative) -> clamp to a safe row and
// predicate the accumulate, so all loads can issue before n-dependent control flow.
__global__ __launch_bounds__(256) void gather(const int* __restrict__ cnt,
                                              const int* __restrict__ bucket,
                                              const float* __restrict__ uemb,
                                              const float* __restrict__ iemb,
                                              float* __restrict__ agg) {
    int s = blockIdx.x * 4 + (threadIdx.x >> 6);
    int lane = threadIdx.x & 63;
    int n = cnt[s]; if (n > CAP) n = CAP;
    const int* bk = bucket + s * CAP;

    float2 v[4];
#pragma unroll
    for (int k = 0; k < 4; ++k) {
        int src = bk[k];
        if (src < 0 || src >= NUM_NODES) src = 0;      // poison guard (value unused)
        const float* row = (src < NUM_USERS)
            ? uemb + (size_t)src * DIM
            : iemb + (size_t)(src - NUM_USERS) * DIM;
        v[k] = ((const float2*)row)[lane];             // 4 independent 512B gathers
    }
    float2 acc = {0.f, 0.f};
#pragma unroll
    for (int k = 0; k < 4; ++k)
        if (k < n) { acc.x += v[k].x; acc.y += v[k].y; }
    for (int k = 4; k < n; ++k) {                      // rare tail (P(n>4) ~ 5%)
        int src = bk[k];
        const float* row = (src < NUM_USERS)
            ? uemb + (size_t)src * DIM
            : iemb + (size_t)(src - NUM_USERS) * DIM;
        float2 t = ((const float2*)row)[lane];
        acc.x += t.x; acc.y += t.y;
    }
    ((float2*)(agg + (size_t)s * DIM))[lane] = acc;
}

// ---- K3b: transform. prop[s][j] = b[j] + agg[s]·W[j]. ----
// A tile in LDS (coalesced load), W row per thread in VGPRs, 4 slots concurrently
// per thread -> 4 independent accumulator chains, broadcast LDS reads.
#define SPB 32
__global__ __launch_bounds__(256) void transform(const float* __restrict__ agg,
                                                 const float* __restrict__ W,
                                                 const float* __restrict__ bias,
                                                 float* __restrict__ prop) {
    __shared__ float4 lds[SPB * DIM / 4];              // 32x128 f32 = 16 KB
    int base = blockIdx.x * SPB;
    int tid = threadIdx.x;

    const float4* ag = (const float4*)(agg + (size_t)base * DIM);
#pragma unroll
    for (int i = 0; i < SPB * DIM / 4 / 256; ++i)      // 4 x float4 per thread
        lds[i * 256 + tid] = ag[i * 256 + tid];

    int j = tid & 127;                                 // output column
    int half = tid >> 7;                               // 0/1: which 16 slots
    float4 wj[DIM / 4];
    const float4* wrow = (const float4*)(W + j * DIM);
#pragma unroll
    for (int kk = 0; kk < DIM / 4; ++kk) wj[kk] = wrow[kk];
    float bj = bias[j];
    __syncthreads();

#pragma unroll
    for (int g = 0; g < 4; ++g) {
        int s0 = half * 16 + g * 4;
        const float4* a0 = lds + (s0 + 0) * (DIM / 4);
        const float4* a1 = lds + (s0 + 1) * (DIM / 4);
        const float4* a2 = lds + (s0 + 2) * (DIM / 4);
        const float4* a3 = lds + (s0 + 3) * (DIM / 4);
        float c0 = bj, c1 = bj, c2 = bj, c3 = bj;
#pragma unroll
        for (int kk = 0; kk < DIM / 4; ++kk) {
            float4 w4 = wj[kk];
            float4 x0 = a0[kk], x1 = a1[kk], x2 = a2[kk], x3 = a3[kk];
            c0 += x0.x * w4.x + x0.y * w4.y + x0.z * w4.z + x0.w * w4.w;
            c1 += x1.x * w4.x + x1.y * w4.y + x1.z * w4.z + x1.w * w4.w;
            c2 += x2.x * w4.x + x2.y * w4.y + x2.z * w4.z + x2.w * w4.w;
            c3 += x3.x * w4.x + x3.y * w4.y + x3.z * w4.z + x3.w * w4.w;
        }
        prop[(size_t)(base + s0 + 0) * DIM + j] = c0;
        prop[(size_t)(base + s0 + 1) * DIM + j] = c1;
        prop[(size_t)(base + s0 + 2) * DIM + j] = c2;
        prop[(size_t)(base + s0 + 3) * DIM + j] = c3;
    }
}

// ---- K4: out[b] = dot(prop[slot(user)], prop[slot(item)]); one wave per output ----
__global__ void final_dot(const int* __restrict__ uidx, const int* __restrict__ iidx,
                          const int* __restrict__ map, const float* __restrict__ prop,
                          float* __restrict__ out) {
    int o = blockIdx.x * 4 + (threadIdx.x >> 6);
    if (o >= BATCH) return;
    int lane = threadIdx.x & 63;
    int su = map[uidx[o]];
    int si = map[NUM_USERS + iidx[o]];
    float2 a = ((const float2*)(prop + (size_t)su * DIM))[lane];
    float2 c = ((const float2*)(prop + (size_t)si * DIM))[lane];
    float v = a.x * c.x + a.y * c.y;
#pragma unroll
    for (int off = 32; off > 0; off >>= 1) v += __shfl_down(v, off);
    if (lane == 0) out[o] = v;
}

extern "C" void kernel_launch(void* const* d_in, const int* in_sizes, int n_in,
                              void* d_out, int out_size, void* d_ws, size_t ws_size,
                              hipStream_t stream) {
    const int*   uidx  = (const int*)d_in[0];
    const int*   iidx  = (const int*)d_in[1];
    const float* uemb  = (const float*)d_in[2];
    const float* iemb  = (const float*)d_in[3];
    const float* W     = (const float*)d_in[4];
    const float* bias  = (const float*)d_in[5];
    const int*   edges = (const int*)d_in[6];
    float*       out   = (float*)d_out;

    char* ws = (char*)d_ws;
    int*   map    = (int*)ws;                          // 300000*4 = 1.2 MB
    int*   cnt    = (int*)(ws + (2u << 20));           // 128 KB
    int*   bucket = (int*)(ws + (3u << 20));           // 4 MB
    float* agg    = (float*)(ws + (8u << 20));         // 16 MB
    float* prop   = (float*)(ws + (8u << 20) + (size_t)NSLOTS * DIM * 4);  // 16 MB

    hipMemsetAsync(map, 0xFF, NUM_NODES * sizeof(int), stream);   // map = -1
    hipMemsetAsync(cnt, 0, NSLOTS * sizeof(int), stream);

    build_map<<<(NSLOTS + 255) / 256, 256, 0, stream>>>(uidx, iidx, map);
    bin_edges<<<(NUM_EDGES + 255) / 256, 256, 0, stream>>>(edges, map, cnt, bucket);
    gather<<<NSLOTS / 4, 256, 0, stream>>>(cnt, bucket, uemb, iemb, agg);
    transform<<<NSLOTS / SPB, 256, 0, stream>>>(agg, W, bias, prop);
    final_dot<<<(BATCH + 3) / 4, 256, 0, stream>>>(uidx, iidx, map, prop, out);
}

// Round 5
// 213.822 us; speedup vs baseline: 1.6672x; 1.1138x over previous
//
#include <hip/hip_runtime.h>

#define NUM_USERS 200000
#define NUM_ITEMS 100000
#define NUM_NODES 300000
#define NUM_EDGES 600000
#define DIM      128
#define BATCH    16384
#define NSLOTS   (2 * BATCH)   // 32768 candidate slots
#define CAP      32            // max captured in-degree (Poisson(2): P(>32) ~ 1e-27)

typedef __attribute__((ext_vector_type(4))) float f32x4;
typedef __attribute__((ext_vector_type(8))) short bf16x8;

static __device__ __forceinline__ ushort f2bf(float x) {   // RNE, finite inputs
    unsigned u = __float_as_uint(x);
    return (ushort)((u + 0x7FFF + ((u >> 16) & 1)) >> 16);
}

// ---- K0: W (f32 128x128) -> bf16 ----
__global__ void wconv(const float* __restrict__ W, ushort* __restrict__ Wb) {
    int t = blockIdx.x * 256 + threadIdx.x;        // 16 blocks x 256 = 4096 threads x 4
    float4 v = ((const float4*)W)[t];
    ushort4 o = { f2bf(v.x), f2bf(v.y), f2bf(v.z), f2bf(v.w) };
    ((ushort4*)Wb)[t] = o;
}

// ---- K1: node -> slot map via CAS dedup. map pre-set to -1 by memset(0xFF). ----
__global__ void build_map(const int* __restrict__ uidx, const int* __restrict__ iidx,
                          int* __restrict__ map) {
    int t = blockIdx.x * 256 + threadIdx.x;
    if (t >= NSLOTS) return;
    int node = (t < BATCH) ? uidx[t] : (NUM_USERS + iidx[t - BATCH]);
    atomicCAS(&map[node], -1, t);
}

// ---- K2: bucket contributing edges by destination slot (one int atomic/edge). ----
__global__ void bin_edges(const int* __restrict__ edges, const int* __restrict__ map,
                          int* __restrict__ cnt, int* __restrict__ bucket) {
    int e = blockIdx.x * 256 + threadIdx.x;
    if (e >= NUM_EDGES) return;
    int dst = edges[NUM_EDGES + e];
    int s = map[dst];
    if (s < 0) return;                    // ~90% exit
    int src = edges[e];
    int p = atomicAdd(&cnt[s], 1);
    if (p < CAP) bucket[s * CAP + p] = src;
}

// ---- K3a: gather. One wave per slot; first 4 row-loads issued in parallel. ----
// Output agg in bf16 (halves downstream traffic; accumulate stays f32).
__global__ __launch_bounds__(256) void gather(const int* __restrict__ cnt,
                                              const int* __restrict__ bucket,
                                              const float* __restrict__ uemb,
                                              const float* __restrict__ iemb,
                                              ushort* __restrict__ aggb) {
    int s = blockIdx.x * 4 + (threadIdx.x >> 6);
    int lane = threadIdx.x & 63;
    int n = cnt[s]; if (n > CAP) n = CAP;
    const int* bk = bucket + s * CAP;

    float2 v[4];
#pragma unroll
    for (int k = 0; k < 4; ++k) {
        int src = bk[k];
        if (src < 0 || src >= NUM_NODES) src = 0;      // poison guard (value unused)
        const float* row = (src < NUM_USERS)
            ? uemb + (size_t)src * DIM
            : iemb + (size_t)(src - NUM_USERS) * DIM;
        v[k] = ((const float2*)row)[lane];             // 4 independent 512B gathers
    }
    float2 acc = {0.f, 0.f};
#pragma unroll
    for (int k = 0; k < 4; ++k)
        if (k < n) { acc.x += v[k].x; acc.y += v[k].y; }
    for (int k = 4; k < n; ++k) {                      // rare tail (P(n>4) ~ 5%)
        int src = bk[k];
        const float* row = (src < NUM_USERS)
            ? uemb + (size_t)src * DIM
            : iemb + (size_t)(src - NUM_USERS) * DIM;
        float2 t = ((const float2*)row)[lane];
        acc.x += t.x; acc.y += t.y;
    }
    ushort2 ob = { f2bf(acc.x), f2bf(acc.y) };
    ((ushort2*)(aggb + (size_t)s * DIM))[lane] = ob;
}

// ---- K3b: transform via MFMA. prop = agg @ W^T + b. ----
// One wave per 16-slot group; 8 j-tiles x 4 k-steps of mfma_f32_16x16x32_bf16.
// A and B fragments use the SAME (lane,elem)->k packing (contiguous 8), so the
// hardware's internal k-permutation cancels; C/D layout col=lane&15,
// row=(lane>>4)*4+reg is the HW-verified mapping.
__global__ __launch_bounds__(256) void transform_mfma(
        const ushort* __restrict__ aggb, const ushort* __restrict__ Wb,
        const float* __restrict__ bias, float* __restrict__ prop) {
    int wave = threadIdx.x >> 6, lane = threadIdx.x & 63;
    int lr = lane & 15, lg = lane >> 4;
    int s0 = blockIdx.x * 64 + wave * 16;

    f32x4 acc[8];
#pragma unroll
    for (int jt = 0; jt < 8; ++jt) acc[jt] = (f32x4){0.f, 0.f, 0.f, 0.f};

    const ushort* pa = aggb + (size_t)(s0 + lr) * DIM + lg * 8;  // A: row s0+lr
    const ushort* pw = Wb + lr * DIM + lg * 8;                   // B: col j = jt*16+lr
#pragma unroll
    for (int ks = 0; ks < 4; ++ks) {
        bf16x8 af = *(const bf16x8*)(pa + ks * 32);
#pragma unroll
        for (int jt = 0; jt < 8; ++jt) {
            bf16x8 wf = *(const bf16x8*)(pw + jt * 16 * DIM + ks * 32);
            acc[jt] = __builtin_amdgcn_mfma_f32_16x16x32_bf16(af, wf, acc[jt], 0, 0, 0);
        }
    }
#pragma unroll
    for (int jt = 0; jt < 8; ++jt) {
        float bj = bias[jt * 16 + lr];
#pragma unroll
        for (int r = 0; r < 4; ++r)
            prop[(size_t)(s0 + lg * 4 + r) * DIM + jt * 16 + lr] = acc[jt][r] + bj;
    }
}

// ---- K4: out[b] = dot(prop[slot(user)], prop[slot(item)]); one wave per output ----
__global__ void final_dot(const int* __restrict__ uidx, const int* __restrict__ iidx,
                          const int* __restrict__ map, const float* __restrict__ prop,
                          float* __restrict__ out) {
    int o = blockIdx.x * 4 + (threadIdx.x >> 6);
    if (o >= BATCH) return;
    int lane = threadIdx.x & 63;
    int su = map[uidx[o]];
    int si = map[NUM_USERS + iidx[o]];
    float2 a = ((const float2*)(prop + (size_t)su * DIM))[lane];
    float2 c = ((const float2*)(prop + (size_t)si * DIM))[lane];
    float v = a.x * c.x + a.y * c.y;
#pragma unroll
    for (int off = 32; off > 0; off >>= 1) v += __shfl_down(v, off);
    if (lane == 0) out[o] = v;
}

extern "C" void kernel_launch(void* const* d_in, const int* in_sizes, int n_in,
                              void* d_out, int out_size, void* d_ws, size_t ws_size,
                              hipStream_t stream) {
    const int*   uidx  = (const int*)d_in[0];
    const int*   iidx  = (const int*)d_in[1];
    const float* uemb  = (const float*)d_in[2];
    const float* iemb  = (const float*)d_in[3];
    const float* W     = (const float*)d_in[4];
    const float* bias  = (const float*)d_in[5];
    const int*   edges = (const int*)d_in[6];
    float*       out   = (float*)d_out;

    char* ws = (char*)d_ws;
    int*    map    = (int*)ws;                         // 300000*4 = 1.2 MB
    int*    cnt    = (int*)(ws + (2u << 20));          // 128 KB
    int*    bucket = (int*)(ws + (3u << 20));          // 4 MB
    ushort* Wb     = (ushort*)(ws + (7u << 20));       // 32 KB
    ushort* aggb   = (ushort*)(ws + (8u << 20));       // 32768*128*2 = 8 MB
    float*  prop   = (float*)(ws + (16u << 20));       // 16 MB

    hipMemsetAsync(map, 0xFF, NUM_NODES * sizeof(int), stream);   // map = -1
    hipMemsetAsync(cnt, 0, NSLOTS * sizeof(int), stream);

    wconv<<<16, 256, 0, stream>>>(W, Wb);
    build_map<<<(NSLOTS + 255) / 256, 256, 0, stream>>>(uidx, iidx, map);
    bin_edges<<<(NUM_EDGES + 255) / 256, 256, 0, stream>>>(edges, map, cnt, bucket);
    gather<<<NSLOTS / 4, 256, 0, stream>>>(cnt, bucket, uemb, iemb, aggb);
    transform_mfma<<<NSLOTS / 64, 256, 0, stream>>>(aggb, Wb, bias, prop);
    final_dot<<<(BATCH + 3) / 4, 256, 0, stream>>>(uidx, iidx, map, prop, out);
}

// Round 6
// 210.871 us; speedup vs baseline: 1.6905x; 1.0140x over previous
//
#include <hip/hip_runtime.h>

#define NUM_USERS 200000
#define NUM_ITEMS 100000
#define NUM_NODES 300000
#define NUM_EDGES 600000
#define DIM      128
#define BATCH    16384
#define NSLOTS   (2 * BATCH)   // 32768 candidate slots
#define CAP      32            // max captured in-degree (Poisson(2): P(>32) ~ 1e-27)

typedef __attribute__((ext_vector_type(4))) float f32x4;
typedef __attribute__((ext_vector_type(8))) short bf16x8;

static __device__ __forceinline__ ushort f2bf(float x) {   // RNE, finite inputs
    unsigned u = __float_as_uint(x);
    return (ushort)((u + 0x7FFF + ((u >> 16) & 1)) >> 16);
}
static __device__ __forceinline__ float bf2f(ushort x) {
    return __uint_as_float(((unsigned)x) << 16);
}

// ---- K1 (fused): blocks 0-15 convert W->bf16; blocks 16-143 build node->slot map ----
__global__ __launch_bounds__(256) void init_misc(const float* __restrict__ W,
                                                 ushort* __restrict__ Wb,
                                                 const int* __restrict__ uidx,
                                                 const int* __restrict__ iidx,
                                                 int* __restrict__ map) {
    int b = blockIdx.x;
    if (b < 16) {
        int t = b * 256 + threadIdx.x;             // 4096 threads x float4
        float4 v = ((const float4*)W)[t];
        ushort4 o = { f2bf(v.x), f2bf(v.y), f2bf(v.z), f2bf(v.w) };
        ((ushort4*)Wb)[t] = o;
    } else {
        int t = (b - 16) * 256 + threadIdx.x;
        if (t >= NSLOTS) return;
        int node = (t < BATCH) ? uidx[t] : (NUM_USERS + iidx[t - BATCH]);
        atomicCAS(&map[node], -1, t);              // map pre-set to -1 by memset 0xFF
    }
}

// ---- K2: bucket contributing edges by destination slot (one int atomic/edge). ----
__global__ void bin_edges(const int* __restrict__ edges, const int* __restrict__ map,
                          int* __restrict__ cnt, int* __restrict__ bucket) {
    int e = blockIdx.x * 256 + threadIdx.x;
    if (e >= NUM_EDGES) return;
    int dst = edges[NUM_EDGES + e];
    int s = map[dst];
    if (s < 0) return;                    // ~90% exit
    int src = edges[e];
    int p = atomicAdd(&cnt[s], 1);
    if (p < CAP) bucket[s * CAP + p] = src;
}

// ---- K3: gather. One wave per slot; first 4 row-loads issued in parallel. ----
// Output agg in bf16 (accumulate stays f32).
__global__ __launch_bounds__(256) void gather(const int* __restrict__ cnt,
                                              const int* __restrict__ bucket,
                                              const float* __restrict__ uemb,
                                              const float* __restrict__ iemb,
                                              ushort* __restrict__ aggb) {
    int s = blockIdx.x * 4 + (threadIdx.x >> 6);
    int lane = threadIdx.x & 63;
    int n = cnt[s]; if (n > CAP) n = CAP;
    const int* bk = bucket + s * CAP;

    float2 v[4];
#pragma unroll
    for (int k = 0; k < 4; ++k) {
        int src = bk[k];
        if (src < 0 || src >= NUM_NODES) src = 0;      // poison guard (value unused)
        const float* row = (src < NUM_USERS)
            ? uemb + (size_t)src * DIM
            : iemb + (size_t)(src - NUM_USERS) * DIM;
        v[k] = ((const float2*)row)[lane];             // 4 independent 512B gathers
    }
    float2 acc = {0.f, 0.f};
#pragma unroll
    for (int k = 0; k < 4; ++k)
        if (k < n) { acc.x += v[k].x; acc.y += v[k].y; }
    for (int k = 4; k < n; ++k) {                      // rare tail (P(n>4) ~ 5%)
        int src = bk[k];
        const float* row = (src < NUM_USERS)
            ? uemb + (size_t)src * DIM
            : iemb + (size_t)(src - NUM_USERS) * DIM;
        float2 t = ((const float2*)row)[lane];
        acc.x += t.x; acc.y += t.y;
    }
    ushort2 ob = { f2bf(acc.x), f2bf(acc.y) };
    ((ushort2*)(aggb + (size_t)s * DIM))[lane] = ob;
}

// ---- K4: transform via MFMA, j-split for occupancy. prop(bf16) = agg @ W^T + b ----
// Each wave: one 16-slot tile x 32 output cols (2 MFMA tiles) -> 8192 waves total
// (8 waves/SIMD vs 2 before). A/B fragments share the same (lane,elem)->k packing
// so internal k-permutation cancels; C/D: col=lane&15, row=(lane>>4)*4+reg.
__global__ __launch_bounds__(256) void transform_mfma(
        const ushort* __restrict__ aggb, const ushort* __restrict__ Wb,
        const float* __restrict__ bias, ushort* __restrict__ propb) {
    int gw = blockIdx.x * 4 + (threadIdx.x >> 6);   // global wave id, 0..8191
    int lane = threadIdx.x & 63;
    int stile = gw >> 2;                            // 0..2047: which 16 slots
    int jq = gw & 3;                                // 0..3: which 32 cols
    int lr = lane & 15, lg = lane >> 4;
    int s0 = stile * 16;

    f32x4 acc0 = {0.f, 0.f, 0.f, 0.f}, acc1 = {0.f, 0.f, 0.f, 0.f};
    const ushort* pa = aggb + (size_t)(s0 + lr) * DIM + lg * 8;
    const ushort* pw = Wb + (size_t)(jq * 32 + lr) * DIM + lg * 8;
#pragma unroll
    for (int ks = 0; ks < 4; ++ks) {
        bf16x8 af = *(const bf16x8*)(pa + ks * 32);
        bf16x8 w0 = *(const bf16x8*)(pw + ks * 32);
        bf16x8 w1 = *(const bf16x8*)(pw + 16 * DIM + ks * 32);
        acc0 = __builtin_amdgcn_mfma_f32_16x16x32_bf16(af, w0, acc0, 0, 0, 0);
        acc1 = __builtin_amdgcn_mfma_f32_16x16x32_bf16(af, w1, acc1, 0, 0, 0);
    }
    float b0 = bias[jq * 32 + lr], b1 = bias[jq * 32 + 16 + lr];
#pragma unroll
    for (int r = 0; r < 4; ++r) {
        size_t row = (size_t)(s0 + lg * 4 + r) * DIM;
        propb[row + jq * 32 + lr]      = f2bf(acc0[r] + b0);
        propb[row + jq * 32 + 16 + lr] = f2bf(acc1[r] + b1);
    }
}

// ---- K5: out[b] = dot(prop[slot(user)], prop[slot(item)]); one wave per output ----
__global__ void final_dot(const int* __restrict__ uidx, const int* __restrict__ iidx,
                          const int* __restrict__ map, const ushort* __restrict__ propb,
                          float* __restrict__ out) {
    int o = blockIdx.x * 4 + (threadIdx.x >> 6);
    if (o >= BATCH) return;
    int lane = threadIdx.x & 63;
    int su = map[uidx[o]];
    int si = map[NUM_USERS + iidx[o]];
    ushort2 a = ((const ushort2*)(propb + (size_t)su * DIM))[lane];
    ushort2 c = ((const ushort2*)(propb + (size_t)si * DIM))[lane];
    float v = bf2f(a.x) * bf2f(c.x) + bf2f(a.y) * bf2f(c.y);
#pragma unroll
    for (int off = 32; off > 0; off >>= 1) v += __shfl_down(v, off);
    if (lane == 0) out[o] = v;
}

extern "C" void kernel_launch(void* const* d_in, const int* in_sizes, int n_in,
                              void* d_out, int out_size, void* d_ws, size_t ws_size,
                              hipStream_t stream) {
    const int*   uidx  = (const int*)d_in[0];
    const int*   iidx  = (const int*)d_in[1];
    const float* uemb  = (const float*)d_in[2];
    const float* iemb  = (const float*)d_in[3];
    const float* W     = (const float*)d_in[4];
    const float* bias  = (const float*)d_in[5];
    const int*   edges = (const int*)d_in[6];
    float*       out   = (float*)d_out;

    char* ws = (char*)d_ws;
    int*    map    = (int*)ws;                         // 300000*4 = 1.2 MB
    int*    cnt    = (int*)(ws + (2u << 20));          // 128 KB
    int*    bucket = (int*)(ws + (3u << 20));          // 4 MB
    ushort* Wb     = (ushort*)(ws + (7u << 20));       // 32 KB
    ushort* aggb   = (ushort*)(ws + (8u << 20));       // 8 MB
    ushort* propb  = (ushort*)(ws + (16u << 20));      // 8 MB

    hipMemsetAsync(map, 0xFF, NUM_NODES * sizeof(int), stream);   // map = -1
    hipMemsetAsync(cnt, 0, NSLOTS * sizeof(int), stream);

    init_misc<<<16 + (NSLOTS + 255) / 256, 256, 0, stream>>>(W, Wb, uidx, iidx, map);
    bin_edges<<<(NUM_EDGES + 255) / 256, 256, 0, stream>>>(edges, map, cnt, bucket);
    gather<<<NSLOTS / 4, 256, 0, stream>>>(cnt, bucket, uemb, iemb, aggb);
    transform_mfma<<<NSLOTS / 16, 256, 0, stream>>>(aggb, Wb, bias, propb);
    final_dot<<<(BATCH + 3) / 4, 256, 0, stream>>>(uidx, iidx, map, propb, out);
}